// Round 12
// baseline (188.771 us; speedup 1.0000x reference)
//
#include <hip/hip_runtime.h>
#include <math.h>

#define NQ 8
#define FDIM 2048
#define EPSV 1e-5f

typedef __attribute__((ext_vector_type(8))) short short8v;   // 8 bf16 = 4 VGPR
typedef __attribute__((ext_vector_type(16))) float f32x16;   // 32x32 C/D frag

__device__ __forceinline__ unsigned pk_bf16(float lo, float hi) {
    unsigned r;
    asm("v_cvt_pk_bf16_f32 %0, %1, %2" : "=v"(r) : "v"(lo), "v"(hi));
    return r;
}

__device__ __forceinline__ short8v pack4(unsigned a, unsigned b, unsigned c, unsigned d) {
    uint4 w; w.x = a; w.y = b; w.z = c; w.w = d;
    return __builtin_bit_cast(short8v, w);
}

__device__ __forceinline__ float bf16_to_f32(short v) {
    return __builtin_bit_cast(float, (unsigned)((unsigned short)v) << 16);
}

#define MFMA32 __builtin_amdgcn_mfma_f32_32x32x16_bf16

// packed relu (v_pk_max_f32) + bf16 repack of a C1 fragment into 2 A-frags
#define RP(C, d0, d1)                                                   \
  { const f32x16 m_ = __builtin_elementwise_max(C, zeroC);              \
    d0 = pack4(pk_bf16(m_[0],  m_[1]),  pk_bf16(m_[2],  m_[3]),         \
               pk_bf16(m_[4],  m_[5]),  pk_bf16(m_[6],  m_[7]));        \
    d1 = pack4(pk_bf16(m_[8],  m_[9]),  pk_bf16(m_[10], m_[11]),        \
               pk_bf16(m_[12], m_[13]), pk_bf16(m_[14], m_[15])); }

// R12: 16 waves (4/SIMD) x 12-MFMA ITER = interleave product 48 (prev best 24).
// Unlocked by R11's measured VGPR=100 <= the 128 cap at 16 waves. Partial-f
// park in bf16 keeps LDS at 136 KB.
#define ITER(AUSE, ALOAD, B0USE, B1USE, C2IDX)                          \
  {                                                                     \
    short8v p00, p01, p10, p11;                                         \
    RP(C1_0, p00, p01); RP(C1_1, p10, p11);                             \
    C1_0 = MFMA32(AUSE, b1S0, zeroC, 0, 0, 0);                          \
    C1_1 = MFMA32(AUSE, b1S1, zeroC, 0, 0, 0);                          \
    acc0 = MFMA32(p00, B0USE, acc0, 0, 0, 0);                           \
    acc1 = MFMA32(p10, B0USE, acc1, 0, 0, 0);                           \
    acc0 = MFMA32(p01, B1USE, acc0, 0, 0, 0);                           \
    acc1 = MFMA32(p11, B1USE, acc1, 0, 0, 0);                           \
    short8v p20, p21, p30, p31;                                         \
    RP(C1_2, p20, p21); RP(C1_3, p30, p31);                             \
    C1_2 = MFMA32(AUSE, b1S2, zeroC, 0, 0, 0);                          \
    C1_3 = MFMA32(AUSE, b1S3, zeroC, 0, 0, 0);                          \
    acc2 = MFMA32(p20, B0USE, acc2, 0, 0, 0);                           \
    acc3 = MFMA32(p30, B0USE, acc3, 0, 0, 0);                           \
    acc2 = MFMA32(p21, B1USE, acc2, 0, 0, 0);                           \
    acc3 = MFMA32(p31, B1USE, acc3, 0, 0, 0);                           \
    ALOAD = *reinterpret_cast<const short8v*>(W1p + (C2IDX) * 512);     \
    B0USE = *reinterpret_cast<const short8v*>(W2p + (C2IDX) * 32);      \
    B1USE = *reinterpret_cast<const short8v*>(W2p + (C2IDX) * 32 + 16); \
  }

__launch_bounds__(1024, 1)
__global__ void qtb_kernel(const float* __restrict__ x,
                           const float* __restrict__ theta,
                           const float* __restrict__ phi,
                           const float* __restrict__ W1,
                           const float* __restrict__ b1,
                           const float* __restrict__ W2,
                           const float* __restrict__ b2,
                           const float* __restrict__ g1,
                           const float* __restrict__ be1,
                           const float* __restrict__ g2,
                           const float* __restrict__ be2,
                           float* __restrict__ out)
{
    __shared__ short W1f[64 * 512];    // A-frag order, 64 KB
    __shared__ short W2s[8 * 2056];    // quad-permuted k, ~32 KB
    __shared__ short park[16][1024];   // per-wave partial f, bf16, 32 KB
    __shared__ float hLds[256 * 8];    // h parked for the epilogue, 8 KB

    const int tid  = threadIdx.x;
    const int lane = tid & 63;
    const int wid  = tid >> 6;      // 0..15
    const int g    = wid & 1;       // token half (128 tokens)
    const int q    = wid >> 1;      // f-eighth 0..7 (8 chunks each)
    const int hi2  = lane >> 5;
    const int il   = lane & 31;
    const int tbase = blockIdx.x * 256 + g * 128;

    // ---- Phase A: x loads first (prologue depends only on these) ----
    const float4 xA0 = reinterpret_cast<const float4*>(x + (size_t)(tbase + lane) * NQ)[0];
    const float4 xA1 = reinterpret_cast<const float4*>(x + (size_t)(tbase + lane) * NQ)[1];
    const float4 xB0 = reinterpret_cast<const float4*>(x + (size_t)(tbase + 64 + lane) * NQ)[0];
    const float4 xB1 = reinterpret_cast<const float4*>(x + (size_t)(tbase + 64 + lane) * NQ)[1];

    // ---- Phase B: staging loads into registers (hide under Phase C) ----
    float4 w1lo[2], w1hi[2]; float bk2[2];
#pragma unroll
    for (int it = 0; it < 2; ++it) {
        const int k = tid + it * 1024;
        w1lo[it] = *reinterpret_cast<const float4*>(W1 + (size_t)k * NQ);
        w1hi[it] = *reinterpret_cast<const float4*>(W1 + (size_t)k * NQ + 4);
        bk2[it]  = b1[k];
    }
    float4 w2v[4];
#pragma unroll
    for (int it = 0; it < 4; ++it) {
        const int idx = tid + it * 1024;
        const int i = idx >> 9, kq = idx & 511;
        w2v[it] = *reinterpret_cast<const float4*>(W2 + (size_t)i * FDIM + kq * 4);
    }

    // ---- Phase C: per-token prologue (2 tokens per lane) ----
    float h[2][8];
    unsigned zpkt[2][4];
#pragma unroll
    for (int tt = 0; tt < 2; ++tt) {
        const float4 x0 = tt ? xB0 : xA0;
        const float4 x1 = tt ? xB1 : xA1;
        const float xv[8] = {x0.x, x0.y, x0.z, x0.w, x1.x, x1.y, x1.z, x1.w};

        float c[8];
#pragma unroll
        for (int j = 0; j < 8; ++j) c[j] = __cosf(xv[j] + theta[j]);
        float attn[8];
        attn[0] = ((c[1] * c[2]) * (c[3] * c[4])) * ((c[5] * c[6]) * c[7]);
        {
            float p = c[0];
#pragma unroll
            for (int j = 1; j < 8; ++j) { p *= c[j]; attn[j] = p; }
        }
        float s[8];
#pragma unroll
        for (int j = 0; j < 8; ++j) s[j] = xv[j] + attn[j];
        float mean = 0.f;
#pragma unroll
        for (int j = 0; j < 8; ++j) mean += s[j];
        mean *= 0.125f;
        float var = 0.f;
#pragma unroll
        for (int j = 0; j < 8; ++j) { float d = s[j] - mean; var = fmaf(d, d, var); }
        var *= 0.125f;
        const float rs = rsqrtf(var + EPSV);
#pragma unroll
        for (int j = 0; j < 8; ++j) h[tt][j] = (s[j] - mean) * rs * g1[j] + be1[j];

        float zv[8];
#pragma unroll
        for (int j = 0; j < 8; ++j) zv[j] = __cosf(phi[j]) * __cosf(h[tt][j]);
#pragma unroll
        for (int p = 0; p < 4; ++p) zpkt[tt][p] = pk_bf16(zv[2 * p], zv[2 * p + 1]);
    }

    // park h for the epilogue (only the combine waves wid 0/1 need it)
    if (q == 0) {
        float4* hp0 = reinterpret_cast<float4*>(&hLds[(g * 128 + lane) * 8]);
        hp0[0] = make_float4(h[0][0], h[0][1], h[0][2], h[0][3]);
        hp0[1] = make_float4(h[0][4], h[0][5], h[0][6], h[0][7]);
        float4* hp1 = reinterpret_cast<float4*>(&hLds[(g * 128 + 64 + lane) * 8]);
        hp1[0] = make_float4(h[1][0], h[1][1], h[1][2], h[1][3]);
        hp1[1] = make_float4(h[1][4], h[1][5], h[1][6], h[1][7]);
    }

    // z B-fragments for 4 token-subtiles
    unsigned zs[2][2][4];
#pragma unroll
    for (int tt = 0; tt < 2; ++tt)
#pragma unroll
        for (int p = 0; p < 4; ++p) {
            zs[tt][0][p] = (unsigned)__shfl((int)zpkt[tt][p], il);
            zs[tt][1][p] = (unsigned)__shfl((int)zpkt[tt][p], 32 + il);
        }
    const unsigned biasv = 0x00003f80u;  // bf16(1.0) low half
    const short8v b1S0 = pack4(hi2 ? zs[0][0][2] : zs[0][0][0],
                               hi2 ? zs[0][0][3] : zs[0][0][1],
                               hi2 ? 0u : biasv, 0u);
    const short8v b1S1 = pack4(hi2 ? zs[0][1][2] : zs[0][1][0],
                               hi2 ? zs[0][1][3] : zs[0][1][1],
                               hi2 ? 0u : biasv, 0u);
    const short8v b1S2 = pack4(hi2 ? zs[1][0][2] : zs[1][0][0],
                               hi2 ? zs[1][0][3] : zs[1][0][1],
                               hi2 ? 0u : biasv, 0u);
    const short8v b1S3 = pack4(hi2 ? zs[1][1][2] : zs[1][1][0],
                               hi2 ? zs[1][1][3] : zs[1][1][1],
                               hi2 ? 0u : biasv, 0u);

    // ---- Phase D: pack + LDS-write staged weights, then barrier ----
#pragma unroll
    for (int it = 0; it < 2; ++it) {
        const int k = tid + it * 1024;
        uint4 d0, d1;
        d0.x = pk_bf16(w1lo[it].x, w1lo[it].y); d0.y = pk_bf16(w1lo[it].z, w1lo[it].w);
        d0.z = pk_bf16(bk2[it], 0.f);           d0.w = 0u;
        d1.x = pk_bf16(w1hi[it].x, w1hi[it].y); d1.y = pk_bf16(w1hi[it].z, w1hi[it].w);
        d1.z = 0u;                              d1.w = 0u;
        *reinterpret_cast<uint4*>(&W1f[(k >> 5) * 512 + (k & 31) * 8])        = d0;
        *reinterpret_cast<uint4*>(&W1f[(k >> 5) * 512 + ((k & 31) + 32) * 8]) = d1;
    }
#pragma unroll
    for (int it = 0; it < 4; ++it) {
        const int idx = tid + it * 1024;
        const int i = idx >> 9, kq = idx & 511;
        const int k0 = kq * 4;
        const int quad = (k0 >> 2) & 3;
        const int posq = (0x3120 >> (quad * 4)) & 0xF;   // 0->0,1->2,2->1,3->3
        const int dcol = (k0 & ~15) | (posq * 4);
        uint2 pkw; pkw.x = pk_bf16(w2v[it].x, w2v[it].y); pkw.y = pk_bf16(w2v[it].z, w2v[it].w);
        *reinterpret_cast<uint2*>(&W2s[i * 2056 + dcol]) = pkw;
    }
    __syncthreads();

    // ---- k-loop: 8 chunks per wave, FULLY UNROLLED ----
    f32x16 zeroC;
#pragma unroll
    for (int e = 0; e < 16; ++e) zeroC[e] = 0.f;
    f32x16 acc0 = zeroC, acc1 = zeroC, acc2 = zeroC, acc3 = zeroC;

    const int ir = il & 7;
    const short* W1p = &W1f[(q * 8) * 512 + lane * 8];           // + t*512 (imm)
    const short* W2p = &W2s[ir * 2056 + (q * 8) * 32 + hi2 * 8]; // + t*32 (imm)

    short8v A1a = *reinterpret_cast<const short8v*>(W1p);
    short8v B0a = *reinterpret_cast<const short8v*>(W2p);
    short8v B1a = *reinterpret_cast<const short8v*>(W2p + 16);
    f32x16 C1_0 = MFMA32(A1a, b1S0, zeroC, 0, 0, 0);
    f32x16 C1_1 = MFMA32(A1a, b1S1, zeroC, 0, 0, 0);
    f32x16 C1_2 = MFMA32(A1a, b1S2, zeroC, 0, 0, 0);
    f32x16 C1_3 = MFMA32(A1a, b1S3, zeroC, 0, 0, 0);
    short8v A1b = *reinterpret_cast<const short8v*>(W1p + 512);
    short8v B0b = *reinterpret_cast<const short8v*>(W2p + 32);
    short8v B1b = *reinterpret_cast<const short8v*>(W2p + 32 + 16);

#pragma unroll
    for (int t = 0; t < 8; t += 2) {
        ITER(A1b, A1a, B0a, B1a, (t + 2) & 7);   // compile-time indices
        ITER(A1a, A1b, B0b, B1b, (t + 3) & 7);
    }

    // ---- park partial f (cols<8) as bf16: [token][E] layout ----
    if (il < 8) {
        short* fb = &park[wid][0];
#pragma unroll
        for (int r = 0; r < 16; ++r) {
            const int trow = (r & 3) + 8 * (r >> 2) + 4 * hi2;
            fb[trow * 8 + il]        = (short)pk_bf16(acc0[r], 0.f);
            fb[(32 + trow) * 8 + il] = (short)pk_bf16(acc1[r], 0.f);
            fb[(64 + trow) * 8 + il] = (short)pk_bf16(acc2[r], 0.f);
            fb[(96 + trow) * 8 + il] = (short)pk_bf16(acc3[r], 0.f);
        }
    }
    __syncthreads();

    // ---- combine + LN2 + store: waves wid 0/1, 2 tokens per lane ----
    if (q == 0) {
#pragma unroll
        for (int tt = 0; tt < 2; ++tt) {
            const int tloc = tt * 64 + lane;
            float fv[8] = {0.f, 0.f, 0.f, 0.f, 0.f, 0.f, 0.f, 0.f};
#pragma unroll
            for (int qq = 0; qq < 8; ++qq) {
                const short8v pv = *reinterpret_cast<const short8v*>(&park[qq * 2 + g][tloc * 8]);
#pragma unroll
                for (int j = 0; j < 8; ++j) fv[j] += bf16_to_f32(pv[j]);
            }

            const float4 h0 = reinterpret_cast<const float4*>(&hLds[(g * 128 + tloc) * 8])[0];
            const float4 h1 = reinterpret_cast<const float4*>(&hLds[(g * 128 + tloc) * 8])[1];
            const float hv[8] = {h0.x, h0.y, h0.z, h0.w, h1.x, h1.y, h1.z, h1.w};

            float y[8];
#pragma unroll
            for (int j = 0; j < 8; ++j) y[j] = hv[j] + fv[j] + b2[j];
            float mean2 = 0.f;
#pragma unroll
            for (int j = 0; j < 8; ++j) mean2 += y[j];
            mean2 *= 0.125f;
            float var2 = 0.f;
#pragma unroll
            for (int j = 0; j < 8; ++j) { float d = y[j] - mean2; var2 = fmaf(d, d, var2); }
            var2 *= 0.125f;
            const float rs2 = rsqrtf(var2 + EPSV);

            float o[8];
#pragma unroll
            for (int j = 0; j < 8; ++j) o[j] = (y[j] - mean2) * rs2 * g2[j] + be2[j];

            const int token = blockIdx.x * 256 + g * 128 + tloc;
            float4* op = reinterpret_cast<float4*>(out + (size_t)token * NQ);
            op[0] = make_float4(o[0], o[1], o[2], o[3]);
            op[1] = make_float4(o[4], o[5], o[6], o[7]);
        }
    }
}

extern "C" void kernel_launch(void* const* d_in, const int* in_sizes, int n_in,
                              void* d_out, int out_size, void* d_ws, size_t ws_size,
                              hipStream_t stream) {
    const float* x     = (const float*)d_in[0];
    const float* theta = (const float*)d_in[1];
    const float* phi   = (const float*)d_in[2];
    const float* W1    = (const float*)d_in[3];
    const float* b1    = (const float*)d_in[4];
    const float* W2    = (const float*)d_in[5];
    const float* b2    = (const float*)d_in[6];
    const float* g1    = (const float*)d_in[7];
    const float* be1   = (const float*)d_in[8];
    const float* g2    = (const float*)d_in[9];
    const float* be2   = (const float*)d_in[10];
    float* out = (float*)d_out;

    const int ntok = in_sizes[0] / NQ;   // 65536
    const int grid = ntok / 256;         // 256 blocks x 1024 thr, 1 block/CU

    qtb_kernel<<<grid, 1024, 0, stream>>>(x, theta, phi, W1, b1, W2, b2,
                                          g1, be1, g2, be2, out);
}

// Round 13
// 188.689 us; speedup vs baseline: 1.0004x; 1.0004x over previous
//
#include <hip/hip_runtime.h>
#include <math.h>

#define NQ 8
#define FDIM 2048
#define EPSV 1e-5f

typedef __attribute__((ext_vector_type(8))) short short8v;   // 8 bf16 = 4 VGPR
typedef __attribute__((ext_vector_type(16))) float f32x16;   // 32x32 C/D frag

__device__ __forceinline__ unsigned pk_bf16(float lo, float hi) {
    unsigned r;
    asm("v_cvt_pk_bf16_f32 %0, %1, %2" : "=v"(r) : "v"(lo), "v"(hi));
    return r;
}

__device__ __forceinline__ short8v pack4(unsigned a, unsigned b, unsigned c, unsigned d) {
    uint4 w; w.x = a; w.y = b; w.z = c; w.w = d;
    return __builtin_bit_cast(short8v, w);
}

__device__ __forceinline__ float bf16_to_f32(short v) {
    return __builtin_bit_cast(float, (unsigned)((unsigned short)v) << 16);
}

#define MFMA32 __builtin_amdgcn_mfma_f32_32x32x16_bf16

// packed relu (v_pk_max_f32) + bf16 repack of a C1 fragment into 2 A-frags
#define RP(C, d0, d1)                                                   \
  { const f32x16 m_ = __builtin_elementwise_max(C, zeroC);              \
    d0 = pack4(pk_bf16(m_[0],  m_[1]),  pk_bf16(m_[2],  m_[3]),         \
               pk_bf16(m_[4],  m_[5]),  pk_bf16(m_[6],  m_[7]));        \
    d1 = pack4(pk_bf16(m_[8],  m_[9]),  pk_bf16(m_[10], m_[11]),        \
               pk_bf16(m_[12], m_[13]), pk_bf16(m_[14], m_[15])); }

// R13 = R12 with the CORRECT launch bound. R12's 188us was a launch_bounds
// artifact: (1024,1) let hipcc allocate for 8 waves/SIMD -> 64-VGPR cap ->
// ~36 regs/thread spilled in-loop (VGPR=64, FETCH 273MB scratch traffic).
// (1024,4) pins 4 waves/EU = 1 block/CU = 128-VGPR cap >= the ~100 needed.
// Structure: 16 waves (4/SIMD) x 12-MFMA ITER = interleave product 48.
#define ITER(AUSE, ALOAD, B0USE, B1USE, C2IDX)                          \
  {                                                                     \
    short8v p00, p01, p10, p11;                                         \
    RP(C1_0, p00, p01); RP(C1_1, p10, p11);                             \
    C1_0 = MFMA32(AUSE, b1S0, zeroC, 0, 0, 0);                          \
    C1_1 = MFMA32(AUSE, b1S1, zeroC, 0, 0, 0);                          \
    acc0 = MFMA32(p00, B0USE, acc0, 0, 0, 0);                           \
    acc1 = MFMA32(p10, B0USE, acc1, 0, 0, 0);                           \
    acc0 = MFMA32(p01, B1USE, acc0, 0, 0, 0);                           \
    acc1 = MFMA32(p11, B1USE, acc1, 0, 0, 0);                           \
    short8v p20, p21, p30, p31;                                         \
    RP(C1_2, p20, p21); RP(C1_3, p30, p31);                             \
    C1_2 = MFMA32(AUSE, b1S2, zeroC, 0, 0, 0);                          \
    C1_3 = MFMA32(AUSE, b1S3, zeroC, 0, 0, 0);                          \
    acc2 = MFMA32(p20, B0USE, acc2, 0, 0, 0);                           \
    acc3 = MFMA32(p30, B0USE, acc3, 0, 0, 0);                           \
    acc2 = MFMA32(p21, B1USE, acc2, 0, 0, 0);                           \
    acc3 = MFMA32(p31, B1USE, acc3, 0, 0, 0);                           \
    ALOAD = *reinterpret_cast<const short8v*>(W1p + (C2IDX) * 512);     \
    B0USE = *reinterpret_cast<const short8v*>(W2p + (C2IDX) * 32);      \
    B1USE = *reinterpret_cast<const short8v*>(W2p + (C2IDX) * 32 + 16); \
  }

__launch_bounds__(1024, 4)
__global__ void qtb_kernel(const float* __restrict__ x,
                           const float* __restrict__ theta,
                           const float* __restrict__ phi,
                           const float* __restrict__ W1,
                           const float* __restrict__ b1,
                           const float* __restrict__ W2,
                           const float* __restrict__ b2,
                           const float* __restrict__ g1,
                           const float* __restrict__ be1,
                           const float* __restrict__ g2,
                           const float* __restrict__ be2,
                           float* __restrict__ out)
{
    __shared__ short W1f[64 * 512];    // A-frag order, 64 KB
    __shared__ short W2s[8 * 2056];    // quad-permuted k, ~32 KB
    __shared__ short park[16][1024];   // per-wave partial f, bf16, 32 KB
    __shared__ float hLds[256 * 8];    // h parked for the epilogue, 8 KB

    const int tid  = threadIdx.x;
    const int lane = tid & 63;
    const int wid  = tid >> 6;      // 0..15
    const int g    = wid & 1;       // token half (128 tokens)
    const int q    = wid >> 1;      // f-eighth 0..7 (8 chunks each)
    const int hi2  = lane >> 5;
    const int il   = lane & 31;
    const int tbase = blockIdx.x * 256 + g * 128;

    // ---- Phase A: x loads first (prologue depends only on these) ----
    const float4 xA0 = reinterpret_cast<const float4*>(x + (size_t)(tbase + lane) * NQ)[0];
    const float4 xA1 = reinterpret_cast<const float4*>(x + (size_t)(tbase + lane) * NQ)[1];
    const float4 xB0 = reinterpret_cast<const float4*>(x + (size_t)(tbase + 64 + lane) * NQ)[0];
    const float4 xB1 = reinterpret_cast<const float4*>(x + (size_t)(tbase + 64 + lane) * NQ)[1];

    // ---- Phase B: staging loads into registers (hide under Phase C) ----
    float4 w1lo[2], w1hi[2]; float bk2[2];
#pragma unroll
    for (int it = 0; it < 2; ++it) {
        const int k = tid + it * 1024;
        w1lo[it] = *reinterpret_cast<const float4*>(W1 + (size_t)k * NQ);
        w1hi[it] = *reinterpret_cast<const float4*>(W1 + (size_t)k * NQ + 4);
        bk2[it]  = b1[k];
    }
    float4 w2v[4];
#pragma unroll
    for (int it = 0; it < 4; ++it) {
        const int idx = tid + it * 1024;
        const int i = idx >> 9, kq = idx & 511;
        w2v[it] = *reinterpret_cast<const float4*>(W2 + (size_t)i * FDIM + kq * 4);
    }

    // ---- Phase C: per-token prologue (2 tokens per lane) ----
    float h[2][8];
    unsigned zpkt[2][4];
#pragma unroll
    for (int tt = 0; tt < 2; ++tt) {
        const float4 x0 = tt ? xB0 : xA0;
        const float4 x1 = tt ? xB1 : xA1;
        const float xv[8] = {x0.x, x0.y, x0.z, x0.w, x1.x, x1.y, x1.z, x1.w};

        float c[8];
#pragma unroll
        for (int j = 0; j < 8; ++j) c[j] = __cosf(xv[j] + theta[j]);
        float attn[8];
        attn[0] = ((c[1] * c[2]) * (c[3] * c[4])) * ((c[5] * c[6]) * c[7]);
        {
            float p = c[0];
#pragma unroll
            for (int j = 1; j < 8; ++j) { p *= c[j]; attn[j] = p; }
        }
        float s[8];
#pragma unroll
        for (int j = 0; j < 8; ++j) s[j] = xv[j] + attn[j];
        float mean = 0.f;
#pragma unroll
        for (int j = 0; j < 8; ++j) mean += s[j];
        mean *= 0.125f;
        float var = 0.f;
#pragma unroll
        for (int j = 0; j < 8; ++j) { float d = s[j] - mean; var = fmaf(d, d, var); }
        var *= 0.125f;
        const float rs = rsqrtf(var + EPSV);
#pragma unroll
        for (int j = 0; j < 8; ++j) h[tt][j] = (s[j] - mean) * rs * g1[j] + be1[j];

        float zv[8];
#pragma unroll
        for (int j = 0; j < 8; ++j) zv[j] = __cosf(phi[j]) * __cosf(h[tt][j]);
#pragma unroll
        for (int p = 0; p < 4; ++p) zpkt[tt][p] = pk_bf16(zv[2 * p], zv[2 * p + 1]);
    }

    // park h for the epilogue (only the combine waves wid 0/1 need it)
    if (q == 0) {
        float4* hp0 = reinterpret_cast<float4*>(&hLds[(g * 128 + lane) * 8]);
        hp0[0] = make_float4(h[0][0], h[0][1], h[0][2], h[0][3]);
        hp0[1] = make_float4(h[0][4], h[0][5], h[0][6], h[0][7]);
        float4* hp1 = reinterpret_cast<float4*>(&hLds[(g * 128 + 64 + lane) * 8]);
        hp1[0] = make_float4(h[1][0], h[1][1], h[1][2], h[1][3]);
        hp1[1] = make_float4(h[1][4], h[1][5], h[1][6], h[1][7]);
    }

    // z B-fragments for 4 token-subtiles
    unsigned zs[2][2][4];
#pragma unroll
    for (int tt = 0; tt < 2; ++tt)
#pragma unroll
        for (int p = 0; p < 4; ++p) {
            zs[tt][0][p] = (unsigned)__shfl((int)zpkt[tt][p], il);
            zs[tt][1][p] = (unsigned)__shfl((int)zpkt[tt][p], 32 + il);
        }
    const unsigned biasv = 0x00003f80u;  // bf16(1.0) low half
    const short8v b1S0 = pack4(hi2 ? zs[0][0][2] : zs[0][0][0],
                               hi2 ? zs[0][0][3] : zs[0][0][1],
                               hi2 ? 0u : biasv, 0u);
    const short8v b1S1 = pack4(hi2 ? zs[0][1][2] : zs[0][1][0],
                               hi2 ? zs[0][1][3] : zs[0][1][1],
                               hi2 ? 0u : biasv, 0u);
    const short8v b1S2 = pack4(hi2 ? zs[1][0][2] : zs[1][0][0],
                               hi2 ? zs[1][0][3] : zs[1][0][1],
                               hi2 ? 0u : biasv, 0u);
    const short8v b1S3 = pack4(hi2 ? zs[1][1][2] : zs[1][1][0],
                               hi2 ? zs[1][1][3] : zs[1][1][1],
                               hi2 ? 0u : biasv, 0u);

    // ---- Phase D: pack + LDS-write staged weights, then barrier ----
#pragma unroll
    for (int it = 0; it < 2; ++it) {
        const int k = tid + it * 1024;
        uint4 d0, d1;
        d0.x = pk_bf16(w1lo[it].x, w1lo[it].y); d0.y = pk_bf16(w1lo[it].z, w1lo[it].w);
        d0.z = pk_bf16(bk2[it], 0.f);           d0.w = 0u;
        d1.x = pk_bf16(w1hi[it].x, w1hi[it].y); d1.y = pk_bf16(w1hi[it].z, w1hi[it].w);
        d1.z = 0u;                              d1.w = 0u;
        *reinterpret_cast<uint4*>(&W1f[(k >> 5) * 512 + (k & 31) * 8])        = d0;
        *reinterpret_cast<uint4*>(&W1f[(k >> 5) * 512 + ((k & 31) + 32) * 8]) = d1;
    }
#pragma unroll
    for (int it = 0; it < 4; ++it) {
        const int idx = tid + it * 1024;
        const int i = idx >> 9, kq = idx & 511;
        const int k0 = kq * 4;
        const int quad = (k0 >> 2) & 3;
        const int posq = (0x3120 >> (quad * 4)) & 0xF;   // 0->0,1->2,2->1,3->3
        const int dcol = (k0 & ~15) | (posq * 4);
        uint2 pkw; pkw.x = pk_bf16(w2v[it].x, w2v[it].y); pkw.y = pk_bf16(w2v[it].z, w2v[it].w);
        *reinterpret_cast<uint2*>(&W2s[i * 2056 + dcol]) = pkw;
    }
    __syncthreads();

    // ---- k-loop: 8 chunks per wave, FULLY UNROLLED ----
    f32x16 zeroC;
#pragma unroll
    for (int e = 0; e < 16; ++e) zeroC[e] = 0.f;
    f32x16 acc0 = zeroC, acc1 = zeroC, acc2 = zeroC, acc3 = zeroC;

    const int ir = il & 7;
    const short* W1p = &W1f[(q * 8) * 512 + lane * 8];           // + t*512 (imm)
    const short* W2p = &W2s[ir * 2056 + (q * 8) * 32 + hi2 * 8]; // + t*32 (imm)

    short8v A1a = *reinterpret_cast<const short8v*>(W1p);
    short8v B0a = *reinterpret_cast<const short8v*>(W2p);
    short8v B1a = *reinterpret_cast<const short8v*>(W2p + 16);
    f32x16 C1_0 = MFMA32(A1a, b1S0, zeroC, 0, 0, 0);
    f32x16 C1_1 = MFMA32(A1a, b1S1, zeroC, 0, 0, 0);
    f32x16 C1_2 = MFMA32(A1a, b1S2, zeroC, 0, 0, 0);
    f32x16 C1_3 = MFMA32(A1a, b1S3, zeroC, 0, 0, 0);
    short8v A1b = *reinterpret_cast<const short8v*>(W1p + 512);
    short8v B0b = *reinterpret_cast<const short8v*>(W2p + 32);
    short8v B1b = *reinterpret_cast<const short8v*>(W2p + 32 + 16);

#pragma unroll
    for (int t = 0; t < 8; t += 2) {
        ITER(A1b, A1a, B0a, B1a, (t + 2) & 7);   // compile-time indices
        ITER(A1a, A1b, B0b, B1b, (t + 3) & 7);
    }

    // ---- park partial f (cols<8) as bf16: [token][E] layout ----
    if (il < 8) {
        short* fb = &park[wid][0];
#pragma unroll
        for (int r = 0; r < 16; ++r) {
            const int trow = (r & 3) + 8 * (r >> 2) + 4 * hi2;
            fb[trow * 8 + il]        = (short)pk_bf16(acc0[r], 0.f);
            fb[(32 + trow) * 8 + il] = (short)pk_bf16(acc1[r], 0.f);
            fb[(64 + trow) * 8 + il] = (short)pk_bf16(acc2[r], 0.f);
            fb[(96 + trow) * 8 + il] = (short)pk_bf16(acc3[r], 0.f);
        }
    }
    __syncthreads();

    // ---- combine + LN2 + store: waves wid 0/1, 2 tokens per lane ----
    if (q == 0) {
#pragma unroll
        for (int tt = 0; tt < 2; ++tt) {
            const int tloc = tt * 64 + lane;
            float fv[8] = {0.f, 0.f, 0.f, 0.f, 0.f, 0.f, 0.f, 0.f};
#pragma unroll
            for (int qq = 0; qq < 8; ++qq) {
                const short8v pv = *reinterpret_cast<const short8v*>(&park[qq * 2 + g][tloc * 8]);
#pragma unroll
                for (int j = 0; j < 8; ++j) fv[j] += bf16_to_f32(pv[j]);
            }

            const float4 h0 = reinterpret_cast<const float4*>(&hLds[(g * 128 + tloc) * 8])[0];
            const float4 h1 = reinterpret_cast<const float4*>(&hLds[(g * 128 + tloc) * 8])[1];
            const float hv[8] = {h0.x, h0.y, h0.z, h0.w, h1.x, h1.y, h1.z, h1.w};

            float y[8];
#pragma unroll
            for (int j = 0; j < 8; ++j) y[j] = hv[j] + fv[j] + b2[j];
            float mean2 = 0.f;
#pragma unroll
            for (int j = 0; j < 8; ++j) mean2 += y[j];
            mean2 *= 0.125f;
            float var2 = 0.f;
#pragma unroll
            for (int j = 0; j < 8; ++j) { float d = y[j] - mean2; var2 = fmaf(d, d, var2); }
            var2 *= 0.125f;
            const float rs2 = rsqrtf(var2 + EPSV);

            float o[8];
#pragma unroll
            for (int j = 0; j < 8; ++j) o[j] = (y[j] - mean2) * rs2 * g2[j] + be2[j];

            const int token = blockIdx.x * 256 + g * 128 + tloc;
            float4* op = reinterpret_cast<float4*>(out + (size_t)token * NQ);
            op[0] = make_float4(o[0], o[1], o[2], o[3]);
            op[1] = make_float4(o[4], o[5], o[6], o[7]);
        }
    }
}

extern "C" void kernel_launch(void* const* d_in, const int* in_sizes, int n_in,
                              void* d_out, int out_size, void* d_ws, size_t ws_size,
                              hipStream_t stream) {
    const float* x     = (const float*)d_in[0];
    const float* theta = (const float*)d_in[1];
    const float* phi   = (const float*)d_in[2];
    const float* W1    = (const float*)d_in[3];
    const float* b1    = (const float*)d_in[4];
    const float* W2    = (const float*)d_in[5];
    const float* b2    = (const float*)d_in[6];
    const float* g1    = (const float*)d_in[7];
    const float* be1   = (const float*)d_in[8];
    const float* g2    = (const float*)d_in[9];
    const float* be2   = (const float*)d_in[10];
    float* out = (float*)d_out;

    const int ntok = in_sizes[0] / NQ;   // 65536
    const int grid = ntok / 256;         // 256 blocks x 1024 thr, 1 block/CU

    qtb_kernel<<<grid, 1024, 0, stream>>>(x, theta, phi, W1, b1, W2, b2,
                                          g1, be1, g2, be2, out);
}

// Round 15
// 20.209 us; speedup vs baseline: 9.3410x; 9.3370x over previous
//
#include <hip/hip_runtime.h>
#include <math.h>

#define NQ 8
#define FDIM 2048
#define EPSV 1e-5f

typedef __attribute__((ext_vector_type(8))) short short8v;   // 8 bf16 = 4 VGPR
typedef __attribute__((ext_vector_type(16))) float f32x16;   // 32x32 C/D frag

__device__ __forceinline__ unsigned pk_bf16(float lo, float hi) {
    unsigned r;
    asm("v_cvt_pk_bf16_f32 %0, %1, %2" : "=v"(r) : "v"(lo), "v"(hi));
    return r;
}

__device__ __forceinline__ short8v pack4(unsigned a, unsigned b, unsigned c, unsigned d) {
    uint4 w; w.x = a; w.y = b; w.z = c; w.w = d;
    return __builtin_bit_cast(short8v, w);
}

#define MFMA32 __builtin_amdgcn_mfma_f32_32x32x16_bf16

// packed relu (v_pk_max_f32) + bf16 repack of a C1 fragment into 2 A-frags
#define RP(C, d0, d1)                                                   \
  { const f32x16 m_ = __builtin_elementwise_max(C, zeroC);              \
    d0 = pack4(pk_bf16(m_[0],  m_[1]),  pk_bf16(m_[2],  m_[3]),         \
               pk_bf16(m_[4],  m_[5]),  pk_bf16(m_[6],  m_[7]));        \
    d1 = pack4(pk_bf16(m_[8],  m_[9]),  pk_bf16(m_[10], m_[11]),        \
               pk_bf16(m_[12], m_[13]), pk_bf16(m_[14], m_[15])); }

// R15 = R14 with the z-fragment bug fixed. R14's failure: hi2-selection was
// moved BEFORE the shfl, but shfl src lanes 0-31 are all hi2=0 -> hi2=1 lanes
// got z0..z3 instead of z4..z7. Fix: z lives in LDS, so read the needed b64
// DIRECTLY per lane (token g*128+32m+il, words hi2*2..) -- no shuffles at all.
// Head/tail specialization kept: waves 0-3 prologue, waves 4-7 staging (in
// parallel); 4-wave epilogue; loop byte-identical to R11 (best 20.6us).
#define ITER(AUSE, ALOAD, B0USE, B1USE, C2IDX)                          \
  {                                                                     \
    short8v p00, p01, p10, p11;                                         \
    RP(C1_0, p00, p01); RP(C1_1, p10, p11);                             \
    C1_0 = MFMA32(AUSE, b1S0, zeroC, 0, 0, 0);                          \
    C1_1 = MFMA32(AUSE, b1S1, zeroC, 0, 0, 0);                          \
    acc0 = MFMA32(p00, B0USE, acc0, 0, 0, 0);                           \
    acc1 = MFMA32(p10, B0USE, acc1, 0, 0, 0);                           \
    acc0 = MFMA32(p01, B1USE, acc0, 0, 0, 0);                           \
    acc1 = MFMA32(p11, B1USE, acc1, 0, 0, 0);                           \
    short8v p20, p21, p30, p31;                                         \
    RP(C1_2, p20, p21); RP(C1_3, p30, p31);                             \
    C1_2 = MFMA32(AUSE, b1S2, zeroC, 0, 0, 0);                          \
    C1_3 = MFMA32(AUSE, b1S3, zeroC, 0, 0, 0);                          \
    acc2 = MFMA32(p20, B0USE, acc2, 0, 0, 0);                           \
    acc3 = MFMA32(p30, B0USE, acc3, 0, 0, 0);                           \
    acc2 = MFMA32(p21, B1USE, acc2, 0, 0, 0);                           \
    acc3 = MFMA32(p31, B1USE, acc3, 0, 0, 0);                           \
    ALOAD = *reinterpret_cast<const short8v*>(W1p + (C2IDX) * 512);     \
    B0USE = *reinterpret_cast<const short8v*>(W2p + (C2IDX) * 32);      \
    B1USE = *reinterpret_cast<const short8v*>(W2p + (C2IDX) * 32 + 16); \
  }

__launch_bounds__(512, 2)
__global__ void qtb_kernel(const float* __restrict__ x,
                           const float* __restrict__ theta,
                           const float* __restrict__ phi,
                           const float* __restrict__ W1,
                           const float* __restrict__ b1,
                           const float* __restrict__ W2,
                           const float* __restrict__ b2,
                           const float* __restrict__ g1,
                           const float* __restrict__ be1,
                           const float* __restrict__ g2,
                           const float* __restrict__ be2,
                           float* __restrict__ out)
{
    __shared__ short W1f[64 * 512];     // A-frag order, 64 KB
    __shared__ short W2s[8 * 2056];     // quad-permuted k, ~32 KB
    __shared__ float parkF[8][1024];    // per-wave partial f (128 tok x 8), 32 KB
    __shared__ float hLds[256 * 8];     // h for the epilogue, 8 KB
    __shared__ unsigned zLds[256][6];   // zpk words, 24B stride, 6 KB

    const int tid  = threadIdx.x;
    const int lane = tid & 63;
    const int wid  = tid >> 6;      // 0..7
    const int g    = wid & 1;       // loop-role: token half
    const int q    = wid >> 1;      // loop-role: f-quarter 0..3
    const int hi2  = lane >> 5;
    const int il   = lane & 31;
    const int tb   = blockIdx.x * 256;

    if (wid < 4) {
        // ---- prologue waves: 1 token/lane, tokens wid*64+lane ----
        const int tl = wid * 64 + lane;
        const float4 x0 = reinterpret_cast<const float4*>(x + (size_t)(tb + tl) * NQ)[0];
        const float4 x1 = reinterpret_cast<const float4*>(x + (size_t)(tb + tl) * NQ)[1];
        const float xv[8] = {x0.x, x0.y, x0.z, x0.w, x1.x, x1.y, x1.z, x1.w};

        float c[8];
#pragma unroll
        for (int j = 0; j < 8; ++j) c[j] = __cosf(xv[j] + theta[j]);
        float attn[8];
        attn[0] = ((c[1] * c[2]) * (c[3] * c[4])) * ((c[5] * c[6]) * c[7]);
        {
            float p = c[0];
#pragma unroll
            for (int j = 1; j < 8; ++j) { p *= c[j]; attn[j] = p; }
        }
        float s[8];
#pragma unroll
        for (int j = 0; j < 8; ++j) s[j] = xv[j] + attn[j];
        float mean = 0.f;
#pragma unroll
        for (int j = 0; j < 8; ++j) mean += s[j];
        mean *= 0.125f;
        float var = 0.f;
#pragma unroll
        for (int j = 0; j < 8; ++j) { float d = s[j] - mean; var = fmaf(d, d, var); }
        var *= 0.125f;
        const float rs = rsqrtf(var + EPSV);
        float h[8];
#pragma unroll
        for (int j = 0; j < 8; ++j) h[j] = (s[j] - mean) * rs * g1[j] + be1[j];

        float zv[8];
#pragma unroll
        for (int j = 0; j < 8; ++j) zv[j] = __cosf(phi[j]) * __cosf(h[j]);

        uint2 zlo, zhi;
        zlo.x = pk_bf16(zv[0], zv[1]); zlo.y = pk_bf16(zv[2], zv[3]);
        zhi.x = pk_bf16(zv[4], zv[5]); zhi.y = pk_bf16(zv[6], zv[7]);
        *reinterpret_cast<uint2*>(&zLds[tl][0]) = zlo;
        *reinterpret_cast<uint2*>(&zLds[tl][2]) = zhi;

        float4* hp = reinterpret_cast<float4*>(&hLds[tl * 8]);
        hp[0] = make_float4(h[0], h[1], h[2], h[3]);
        hp[1] = make_float4(h[4], h[5], h[6], h[7]);
    } else {
        // ---- staging waves: all W1(+b1) and W2 -> LDS (register-batched) ----
        const int t2 = tid - 256;   // 0..255
        {
            float4 wa[8], wb[8]; float bb[8];
#pragma unroll
            for (int it = 0; it < 8; ++it) {
                const int k = t2 + it * 256;
                wa[it] = *reinterpret_cast<const float4*>(W1 + (size_t)k * NQ);
                wb[it] = *reinterpret_cast<const float4*>(W1 + (size_t)k * NQ + 4);
                bb[it] = b1[k];
            }
#pragma unroll
            for (int it = 0; it < 8; ++it) {
                const int k = t2 + it * 256;
                uint4 d0, d1;
                d0.x = pk_bf16(wa[it].x, wa[it].y); d0.y = pk_bf16(wa[it].z, wa[it].w);
                d0.z = pk_bf16(bb[it], 0.f);        d0.w = 0u;
                d1.x = pk_bf16(wb[it].x, wb[it].y); d1.y = pk_bf16(wb[it].z, wb[it].w);
                d1.z = 0u;                          d1.w = 0u;
                *reinterpret_cast<uint4*>(&W1f[(k >> 5) * 512 + (k & 31) * 8])        = d0;
                *reinterpret_cast<uint4*>(&W1f[(k >> 5) * 512 + ((k & 31) + 32) * 8]) = d1;
            }
        }
#pragma unroll
        for (int bt = 0; bt < 2; ++bt) {
            float4 w[8];
#pragma unroll
            for (int it = 0; it < 8; ++it) {
                const int idx = t2 + (bt * 8 + it) * 256;
                const int i = idx >> 9, kq = idx & 511;
                w[it] = *reinterpret_cast<const float4*>(W2 + (size_t)i * FDIM + kq * 4);
            }
#pragma unroll
            for (int it = 0; it < 8; ++it) {
                const int idx = t2 + (bt * 8 + it) * 256;
                const int i = idx >> 9, kq = idx & 511;
                const int k0 = kq * 4;
                const int quad = (k0 >> 2) & 3;
                const int posq = (0x3120 >> (quad * 4)) & 0xF;   // 0->0,1->2,2->1,3->3
                const int dcol = (k0 & ~15) | (posq * 4);
                uint2 pkw; pkw.x = pk_bf16(w[it].x, w[it].y); pkw.y = pk_bf16(w[it].z, w[it].w);
                *reinterpret_cast<uint2*>(&W2s[i * 2056 + dcol]) = pkw;
            }
        }
    }
    __syncthreads();

    // ---- every wave: z B-fragments DIRECTLY from zLds, per-lane, no shfl.
    // Lane (hi2, il) of subtile m needs words [hi2*2, hi2*2+1] of token
    // g*128 + 32m + il. 4 x ds_read_b64, stride 24B -> <=4-way banks.
    const unsigned biasv = 0x00003f80u;  // bf16(1.0) low half
    const int zcol = hi2 * 2;
    const uint2 z0 = *reinterpret_cast<const uint2*>(&zLds[g * 128 +      il][zcol]);
    const uint2 z1 = *reinterpret_cast<const uint2*>(&zLds[g * 128 + 32 + il][zcol]);
    const uint2 z2 = *reinterpret_cast<const uint2*>(&zLds[g * 128 + 64 + il][zcol]);
    const uint2 z3 = *reinterpret_cast<const uint2*>(&zLds[g * 128 + 96 + il][zcol]);
    const short8v b1S0 = pack4(z0.x, z0.y, hi2 ? 0u : biasv, 0u);
    const short8v b1S1 = pack4(z1.x, z1.y, hi2 ? 0u : biasv, 0u);
    const short8v b1S2 = pack4(z2.x, z2.y, hi2 ? 0u : biasv, 0u);
    const short8v b1S3 = pack4(z3.x, z3.y, hi2 ? 0u : biasv, 0u);

    // ---- k-loop: 16 chunks, FULLY UNROLLED (identical to R11) ----
    f32x16 zeroC;
#pragma unroll
    for (int e = 0; e < 16; ++e) zeroC[e] = 0.f;
    f32x16 acc0 = zeroC, acc1 = zeroC, acc2 = zeroC, acc3 = zeroC;

    const int ir = il & 7;
    const short* W1p = &W1f[(q * 16) * 512 + lane * 8];           // + t*512 (imm)
    const short* W2p = &W2s[ir * 2056 + (q * 16) * 32 + hi2 * 8]; // + t*32 (imm)

    short8v A1a = *reinterpret_cast<const short8v*>(W1p);
    short8v B0a = *reinterpret_cast<const short8v*>(W2p);
    short8v B1a = *reinterpret_cast<const short8v*>(W2p + 16);
    f32x16 C1_0 = MFMA32(A1a, b1S0, zeroC, 0, 0, 0);
    f32x16 C1_1 = MFMA32(A1a, b1S1, zeroC, 0, 0, 0);
    f32x16 C1_2 = MFMA32(A1a, b1S2, zeroC, 0, 0, 0);
    f32x16 C1_3 = MFMA32(A1a, b1S3, zeroC, 0, 0, 0);
    short8v A1b = *reinterpret_cast<const short8v*>(W1p + 512);
    short8v B0b = *reinterpret_cast<const short8v*>(W2p + 32);
    short8v B1b = *reinterpret_cast<const short8v*>(W2p + 32 + 16);

#pragma unroll
    for (int t = 0; t < 16; t += 2) {
        ITER(A1b, A1a, B0a, B1a, (t + 2) & 15);   // compile-time indices
        ITER(A1a, A1b, B0b, B1b, (t + 3) & 15);
    }

    // ---- park partial f (cols<8) in [token][E] layout ----
    if (il < 8) {
        float* fb = &parkF[wid][0];
#pragma unroll
        for (int r = 0; r < 16; ++r) {
            const int trow = (r & 3) + 8 * (r >> 2) + 4 * hi2;
            fb[trow * 8 + il]         = acc0[r];
            fb[(32 + trow) * 8 + il]  = acc1[r];
            fb[(64 + trow) * 8 + il]  = acc2[r];
            fb[(96 + trow) * 8 + il]  = acc3[r];
        }
    }
    __syncthreads();

    // ---- combine + LN2 + store: 4 waves, 1 token per lane ----
    if (wid < 4) {
        const int tl   = wid * 64 + lane;      // 0..255
        const int ge   = tl >> 7;              // token half
        const int tloc = tl & 127;
        float fv[8] = {0.f, 0.f, 0.f, 0.f, 0.f, 0.f, 0.f, 0.f};
#pragma unroll
        for (int qq = 0; qq < 4; ++qq) {
            const float* pb = &parkF[qq * 2 + ge][tloc * 8];
            const float4 f0 = *reinterpret_cast<const float4*>(pb);
            const float4 f1 = *reinterpret_cast<const float4*>(pb + 4);
            fv[0] += f0.x; fv[1] += f0.y; fv[2] += f0.z; fv[3] += f0.w;
            fv[4] += f1.x; fv[5] += f1.y; fv[6] += f1.z; fv[7] += f1.w;
        }

        const float4 h0 = reinterpret_cast<const float4*>(&hLds[tl * 8])[0];
        const float4 h1 = reinterpret_cast<const float4*>(&hLds[tl * 8])[1];
        const float hv[8] = {h0.x, h0.y, h0.z, h0.w, h1.x, h1.y, h1.z, h1.w};

        float y[8];
#pragma unroll
        for (int j = 0; j < 8; ++j) y[j] = hv[j] + fv[j] + b2[j];
        float mean2 = 0.f;
#pragma unroll
        for (int j = 0; j < 8; ++j) mean2 += y[j];
        mean2 *= 0.125f;
        float var2 = 0.f;
#pragma unroll
        for (int j = 0; j < 8; ++j) { float d = y[j] - mean2; var2 = fmaf(d, d, var2); }
        var2 *= 0.125f;
        const float rs2 = rsqrtf(var2 + EPSV);

        float o[8];
#pragma unroll
        for (int j = 0; j < 8; ++j) o[j] = (y[j] - mean2) * rs2 * g2[j] + be2[j];

        float4* op = reinterpret_cast<float4*>(out + (size_t)(tb + tl) * NQ);
        op[0] = make_float4(o[0], o[1], o[2], o[3]);
        op[1] = make_float4(o[4], o[5], o[6], o[7]);
    }
}

extern "C" void kernel_launch(void* const* d_in, const int* in_sizes, int n_in,
                              void* d_out, int out_size, void* d_ws, size_t ws_size,
                              hipStream_t stream) {
    const float* x     = (const float*)d_in[0];
    const float* theta = (const float*)d_in[1];
    const float* phi   = (const float*)d_in[2];
    const float* W1    = (const float*)d_in[3];
    const float* b1    = (const float*)d_in[4];
    const float* W2    = (const float*)d_in[5];
    const float* b2    = (const float*)d_in[6];
    const float* g1    = (const float*)d_in[7];
    const float* be1   = (const float*)d_in[8];
    const float* g2    = (const float*)d_in[9];
    const float* be2   = (const float*)d_in[10];
    float* out = (float*)d_out;

    const int ntok = in_sizes[0] / NQ;   // 65536
    const int grid = ntok / 256;         // 256 blocks x 512 thr, 1 block/CU

    qtb_kernel<<<grid, 512, 0, stream>>>(x, theta, phi, W1, b1, W2, b2,
                                         g1, be1, g2, be2, out);
}